// Round 1
// baseline (323.410 us; speedup 1.0000x reference)
//
#include <hip/hip_runtime.h>
#include <math.h>

#define N_SEQ 1152
#define T_LEN 16
#define DM    256
#define DI    512
#define HWSZ  576

// ---------------------------------------------------------------------------
// K1: xz = x @ in_proj_w^T.  x comes from x_seq (B,T,C,H,W): for fixed (t,c),
// n = b*576 + h*24 + w is contiguous within a b-block. 576 = 9*64, so
// 64-aligned n-tiles stay within one b.  Computes xc_raw (all t, e<512) and
// z_raw (t==15 only, e>=512).
// ---------------------------------------------------------------------------
__global__ __launch_bounds__(256) void k1_inproj(const float* __restrict__ x_seq,
                                                 const float* __restrict__ w,      // (1024,256)
                                                 float* __restrict__ xc_raw,       // [16][1152][512]
                                                 float* __restrict__ z_raw)        // [1152][512]
{
    const int t  = blockIdx.z;
    const int by = blockIdx.y;
    if (t != 15 && by >= 8) return;   // z half only needed at last step
    const int n0 = blockIdx.x * 64;
    const int e0 = by * 64;
    const int b  = n0 / HWSZ;
    const int hw0 = n0 - b * HWSZ;
    const int tid = threadIdx.x;
    const int tx = tid & 15, ty = tid >> 4;

    __shared__ float a_tile[16][64];   // [c][n]
    __shared__ float b_tile[16][68];   // [c][e], padded

    float acc[4][4] = {};  // [n][e]

    const float* xbase = x_seq + (size_t)b * (T_LEN * DM * HWSZ) + (size_t)t * (DM * HWSZ);

    for (int k0 = 0; k0 < DM; k0 += 16) {
        {   // A: 16c x 64n, n-contiguous float4 loads
            int cl = tid >> 4;            // 0..15
            int n4 = (tid & 15) * 4;      // 0..60
            float4 v = *(const float4*)(xbase + (size_t)(k0 + cl) * HWSZ + hw0 + n4);
            *(float4*)&a_tile[cl][n4] = v;
        }
        {   // B: 64e x 16c, transposed into LDS
            int el = tid >> 2;            // 0..63
            int c4 = (tid & 3) * 4;       // 0..12
            float4 v = *(const float4*)&w[(size_t)(e0 + el) * DM + k0 + c4];
            b_tile[c4 + 0][el] = v.x;
            b_tile[c4 + 1][el] = v.y;
            b_tile[c4 + 2][el] = v.z;
            b_tile[c4 + 3][el] = v.w;
        }
        __syncthreads();
#pragma unroll
        for (int kk = 0; kk < 16; ++kk) {
            float4 a = *(const float4*)&a_tile[kk][ty * 4];
            float4 bb = *(const float4*)&b_tile[kk][tx * 4];
            acc[0][0] += a.x * bb.x; acc[0][1] += a.x * bb.y; acc[0][2] += a.x * bb.z; acc[0][3] += a.x * bb.w;
            acc[1][0] += a.y * bb.x; acc[1][1] += a.y * bb.y; acc[1][2] += a.y * bb.z; acc[1][3] += a.y * bb.w;
            acc[2][0] += a.z * bb.x; acc[2][1] += a.z * bb.y; acc[2][2] += a.z * bb.z; acc[2][3] += a.z * bb.w;
            acc[3][0] += a.w * bb.x; acc[3][1] += a.w * bb.y; acc[3][2] += a.w * bb.z; acc[3][3] += a.w * bb.w;
        }
        __syncthreads();
    }

    if (e0 < DI) {
#pragma unroll
        for (int i = 0; i < 4; ++i) {
            float4 v = make_float4(acc[i][0], acc[i][1], acc[i][2], acc[i][3]);
            *(float4*)&xc_raw[((size_t)t * N_SEQ + n0 + ty * 4 + i) * DI + e0 + tx * 4] = v;
        }
    } else {
#pragma unroll
        for (int i = 0; i < 4; ++i) {
            float4 v = make_float4(acc[i][0], acc[i][1], acc[i][2], acc[i][3]);
            *(float4*)&z_raw[(size_t)(n0 + ty * 4 + i) * DI + (e0 - DI) + tx * 4] = v;
        }
    }
}

// ---------------------------------------------------------------------------
// K2: depthwise causal conv (width 4) + bias + SiLU.
// out[t] = silu( sum_j xc_raw[t-j] * conv_w[e][3-j] + conv_b[e] )
// ---------------------------------------------------------------------------
__global__ __launch_bounds__(256) void k2_conv(const float* __restrict__ xc_raw,
                                               const float* __restrict__ conv_w,  // (512,4)
                                               const float* __restrict__ conv_b,
                                               float* __restrict__ xc)
{
    const int idx = blockIdx.x * 256 + threadIdx.x;   // (t*1152+n)*512 + e
    const int e  = idx & (DI - 1);
    const int nt = idx >> 9;
    const int n  = nt % N_SEQ;
    const int t  = nt / N_SEQ;
    float acc = conv_b[e];
#pragma unroll
    for (int j = 0; j < 4; ++j) {
        int tt = t - j;
        if (tt >= 0) acc += xc_raw[((size_t)tt * N_SEQ + n) * DI + e] * conv_w[e * 4 + 3 - j];
    }
    xc[idx] = acc / (1.f + __expf(-acc));
}

// ---------------------------------------------------------------------------
// K3: x_dbl = xc @ x_proj_w^T.  M=18432, N=48, K=512.
// ---------------------------------------------------------------------------
__global__ __launch_bounds__(256) void k3_xproj(const float* __restrict__ xc,
                                                const float* __restrict__ w,   // (48,512)
                                                float* __restrict__ x_dbl)     // [18432][48]
{
    const int r0 = blockIdx.x * 64;
    const int tid = threadIdx.x;
    const int tx = tid & 15;     // col0 = tx*3
    const int ty = tid >> 4;     // row0 = ty*4

    __shared__ float a_tile[16][68];   // [k][row]
    __shared__ float b_tile[16][49];   // [k][col]

    float acc[4][3] = {};

    for (int k0 = 0; k0 < DI; k0 += 16) {
        {   int rl = tid >> 2; int k4 = (tid & 3) * 4;
            float4 v = *(const float4*)&xc[(size_t)(r0 + rl) * DI + k0 + k4];
            a_tile[k4 + 0][rl] = v.x; a_tile[k4 + 1][rl] = v.y;
            a_tile[k4 + 2][rl] = v.z; a_tile[k4 + 3][rl] = v.w; }
        if (tid < 192) {
            int cl = tid >> 2; int k4 = (tid & 3) * 4;
            float4 v = *(const float4*)&w[(size_t)cl * DI + k0 + k4];
            b_tile[k4 + 0][cl] = v.x; b_tile[k4 + 1][cl] = v.y;
            b_tile[k4 + 2][cl] = v.z; b_tile[k4 + 3][cl] = v.w; }
        __syncthreads();
#pragma unroll
        for (int kk = 0; kk < 16; ++kk) {
            float4 a = *(const float4*)&a_tile[kk][ty * 4];
            float b0 = b_tile[kk][tx * 3 + 0];
            float b1 = b_tile[kk][tx * 3 + 1];
            float b2 = b_tile[kk][tx * 3 + 2];
            acc[0][0] += a.x * b0; acc[0][1] += a.x * b1; acc[0][2] += a.x * b2;
            acc[1][0] += a.y * b0; acc[1][1] += a.y * b1; acc[1][2] += a.y * b2;
            acc[2][0] += a.z * b0; acc[2][1] += a.z * b1; acc[2][2] += a.z * b2;
            acc[3][0] += a.w * b0; acc[3][1] += a.w * b1; acc[3][2] += a.w * b2;
        }
        __syncthreads();
    }
#pragma unroll
    for (int i = 0; i < 4; ++i)
#pragma unroll
        for (int c = 0; c < 3; ++c)
            x_dbl[(size_t)(r0 + ty * 4 + i) * 48 + tx * 3 + c] = acc[i][c];
}

// ---------------------------------------------------------------------------
// K4: fused dt_proj + softplus + selective scan + D-residual + silu(z) gate.
// One block (512 threads) per sequence; thread = channel d.  All per-sequence
// inputs staged in LDS once; a single barrier, then a barrier-free t-loop.
// ---------------------------------------------------------------------------
__global__ __launch_bounds__(512) void k4_scan(const float* __restrict__ xc,      // [16][1152][512]
                                               const float* __restrict__ x_dbl,   // [16*1152][48]
                                               const float* __restrict__ dtw,     // (512,16)
                                               const float* __restrict__ dtb,     // (512)
                                               const float* __restrict__ A_log,   // (512,16)
                                               const float* __restrict__ Dp,      // (512)
                                               const float* __restrict__ z_raw,   // [1152][512]
                                               float* __restrict__ y_out)         // [1152][512]
{
    const int n = blockIdx.x;
    const int tid = threadIdx.x;   // channel d

    __shared__ float xs[T_LEN * DI];   // 32 KB
    __shared__ float xd[T_LEN * 48];   // 3 KB

    for (int i = tid; i < T_LEN * DI; i += 512) {
        int t = i >> 9; int e = i & (DI - 1);
        xs[i] = xc[((size_t)t * N_SEQ + n) * DI + e];
    }
    for (int i = tid; i < T_LEN * 48; i += 512) {
        int t = i / 48; int r = i - t * 48;
        xd[i] = x_dbl[((size_t)t * N_SEQ + n) * 48 + r];
    }

    float wreg[16], areg[16], h[16];
#pragma unroll
    for (int r = 0; r < 16; ++r) wreg[r] = dtw[tid * 16 + r];
#pragma unroll
    for (int s = 0; s < 16; ++s) { areg[s] = -__expf(A_log[tid * 16 + s]); h[s] = 0.f; }
    const float bias = dtb[tid];
    __syncthreads();

    for (int t = 0; t < T_LEN; ++t) {
        float dv = bias;
#pragma unroll
        for (int r = 0; r < 16; ++r) dv += xd[t * 48 + r] * wreg[r];
        // softplus, overflow-safe: max(x,0) + log1p(exp(-|x|))
        float dt = fmaxf(dv, 0.f) + log1pf(__expf(-fabsf(dv)));
        float dtx = dt * xs[t * DI + tid];
#pragma unroll
        for (int s = 0; s < 16; ++s) {
            float dA = __expf(dt * areg[s]);
            h[s] = dA * h[s] + dtx * xd[t * 48 + 16 + s];
        }
    }

    float y = 0.f;
#pragma unroll
    for (int s = 0; s < 16; ++s) y += h[s] * xd[15 * 48 + 32 + s];
    y += xs[15 * DI + tid] * Dp[tid];
    float z = z_raw[(size_t)n * DI + tid];
    y *= z / (1.f + __expf(-z));
    y_out[(size_t)n * DI + tid] = y;
}

// ---------------------------------------------------------------------------
// K5: out = y_out @ out_proj_w^T, scattered to (B,C,H,W).  Tile rows = c so
// writes are float4-contiguous along hw (= n within a b-block).
// ---------------------------------------------------------------------------
__global__ __launch_bounds__(256) void k5_outproj(const float* __restrict__ y_in,  // [1152][512]
                                                  const float* __restrict__ w,     // (256,512)
                                                  float* __restrict__ out)         // (2,256,24,24)
{
    const int c0 = blockIdx.x * 64;
    const int n0 = blockIdx.y * 64;
    const int tid = threadIdx.x;
    const int tx = tid & 15, ty = tid >> 4;

    __shared__ float wt[16][68];   // [k][c]
    __shared__ float yt[16][68];   // [k][n]

    float acc[4][4] = {};  // [c][n]

    for (int k0 = 0; k0 < DI; k0 += 16) {
        {   int l = tid >> 2; int k4 = (tid & 3) * 4;
            float4 v = *(const float4*)&w[(size_t)(c0 + l) * DI + k0 + k4];
            wt[k4 + 0][l] = v.x; wt[k4 + 1][l] = v.y; wt[k4 + 2][l] = v.z; wt[k4 + 3][l] = v.w;
            float4 u = *(const float4*)&y_in[(size_t)(n0 + l) * DI + k0 + k4];
            yt[k4 + 0][l] = u.x; yt[k4 + 1][l] = u.y; yt[k4 + 2][l] = u.z; yt[k4 + 3][l] = u.w; }
        __syncthreads();
#pragma unroll
        for (int kk = 0; kk < 16; ++kk) {
            float4 a = *(const float4*)&wt[kk][ty * 4];
            float4 bb = *(const float4*)&yt[kk][tx * 4];
            acc[0][0] += a.x * bb.x; acc[0][1] += a.x * bb.y; acc[0][2] += a.x * bb.z; acc[0][3] += a.x * bb.w;
            acc[1][0] += a.y * bb.x; acc[1][1] += a.y * bb.y; acc[1][2] += a.y * bb.z; acc[1][3] += a.y * bb.w;
            acc[2][0] += a.z * bb.x; acc[2][1] += a.z * bb.y; acc[2][2] += a.z * bb.z; acc[2][3] += a.z * bb.w;
            acc[3][0] += a.w * bb.x; acc[3][1] += a.w * bb.y; acc[3][2] += a.w * bb.z; acc[3][3] += a.w * bb.w;
        }
        __syncthreads();
    }

    const int b = n0 / HWSZ;
    const int hwb = n0 - b * HWSZ + tx * 4;
#pragma unroll
    for (int i = 0; i < 4; ++i) {
        float4 v = make_float4(acc[i][0], acc[i][1], acc[i][2], acc[i][3]);
        *(float4*)&out[(size_t)b * (DM * HWSZ) + (size_t)(c0 + ty * 4 + i) * HWSZ + hwb] = v;
    }
}

// ---------------------------------------------------------------------------
extern "C" void kernel_launch(void* const* d_in, const int* in_sizes, int n_in,
                              void* d_out, int out_size, void* d_ws, size_t ws_size,
                              hipStream_t stream) {
    const float* x_seq     = (const float*)d_in[0];
    const float* in_proj_w = (const float*)d_in[1];
    const float* conv_w    = (const float*)d_in[2];
    const float* conv_b    = (const float*)d_in[3];
    const float* x_proj_w  = (const float*)d_in[4];
    const float* dt_proj_w = (const float*)d_in[5];
    const float* dt_proj_b = (const float*)d_in[6];
    const float* A_log     = (const float*)d_in[7];
    const float* Dp        = (const float*)d_in[8];
    const float* out_proj_w= (const float*)d_in[9];
    float* out = (float*)d_out;
    float* ws  = (float*)d_ws;

    const size_t S1 = (size_t)T_LEN * N_SEQ * DI;     // 9.4M floats
    float* xc_raw = ws;
    float* xc     = ws + S1;
    float* z_raw  = ws + 2 * S1;
    float* x_dbl  = z_raw + (size_t)N_SEQ * DI;
    float* y_out  = x_dbl + (size_t)T_LEN * N_SEQ * 48;

    k1_inproj<<<dim3(18, 16, 16), 256, 0, stream>>>(x_seq, in_proj_w, xc_raw, z_raw);
    k2_conv  <<<(T_LEN * N_SEQ * DI) / 256, 256, 0, stream>>>(xc_raw, conv_w, conv_b, xc);
    k3_xproj <<<288, 256, 0, stream>>>(xc, x_proj_w, x_dbl);
    k4_scan  <<<1152, 512, 0, stream>>>(xc, x_dbl, dt_proj_w, dt_proj_b, A_log, Dp, z_raw, y_out);
    k5_outproj<<<dim3(4, 18), 256, 0, stream>>>(y_out, out_proj_w, out);
}